// Round 6
// baseline (371.525 us; speedup 1.0000x reference)
//
#include <hip/hip_runtime.h>
#include <cstdint>
#include <cstddef>

// TransformerBlock on MI355X (gfx950). bf16 MFMA everywhere, fp32 spine.
// R6: (1) gemm_bt epilogue stages C through LDS and writes full cache lines
//     (R5 counter evidence: WRITE_SIZE 2.1x ideal from 32B partial-line
//     writes). (2) attention processes 128 Q rows/block (two 64-row groups
//     sharing one staged K/V tile) -> half staging traffic, 2x MFMA/barrier.

#define D_MODEL 1024
#define TSEQ    2048
#define BATCH   2
#define NHEADS  16
#define NTOK    (BATCH*TSEQ)   // 4096

typedef __attribute__((ext_vector_type(8))) short bf16x8;
typedef __attribute__((ext_vector_type(4))) float f32x4;
typedef unsigned short ushort_t;

#define AS3(p) ((__attribute__((address_space(3))) unsigned int*)(p))
#define AS1(p) ((const __attribute__((address_space(1))) unsigned int*)(p))

__device__ __forceinline__ unsigned short f2bf(float f){
  union { float f; unsigned u; } v; v.f = f;
  unsigned r = v.u + 0x7fffu + ((v.u >> 16) & 1u);
  return (unsigned short)(r >> 16);
}
__device__ __forceinline__ unsigned pk2bf(float a, float b){
  union { float f; unsigned u; } x, y; x.f = a; y.f = b;
  return __builtin_amdgcn_perm(y.u + 0x8000u, x.u + 0x8000u, 0x07060302u);
}

// ------------- fused weight convert+transpose: fp32 [K][N] -> bf16 [N][K] ---
__global__ __launch_bounds__(256) void wtrans_all(
    const float* __restrict__ w0, ushort_t* __restrict__ o0,
    const float* __restrict__ w1, ushort_t* __restrict__ o1,
    const float* __restrict__ w2, ushort_t* __restrict__ o2,
    const float* __restrict__ w3, ushort_t* __restrict__ o3){
  __shared__ float tile[32][33];
  int bid = blockIdx.x;
  const float* in; ushort_t* out; int K, N, t;
  if (bid < 3072)      { in=w0; out=o0; K=1024; N=3072; t=bid; }
  else if (bid < 4096) { in=w1; out=o1; K=1024; N=1024; t=bid-3072; }
  else if (bid < 8192) { in=w2; out=o2; K=1024; N=4096; t=bid-4096; }
  else                 { in=w3; out=o3; K=4096; N=1024; t=bid-8192; }
  int tx_n = N >> 5;
  int n0 = (t % tx_n)*32, k0 = (t / tx_n)*32;
  int tx = threadIdx.x & 31, ty = threadIdx.x >> 5;   // 32 x 8
  #pragma unroll
  for (int i=0;i<32;i+=8)
    tile[ty+i][tx] = in[(size_t)(k0+ty+i)*N + n0+tx];
  __syncthreads();
  #pragma unroll
  for (int i=0;i<32;i+=8)
    out[(size_t)(n0+ty+i)*K + k0+tx] = f2bf(tile[tx][ty+i]);
}

// ---------------- layernorm: fp32 row[1024] -> bf16 ------------------------
__global__ __launch_bounds__(256) void ln_kernel(const float* __restrict__ x,
                                                 const float* __restrict__ w,
                                                 const float* __restrict__ b,
                                                 ushort_t* __restrict__ out){
  int row = blockIdx.x;
  int tid = threadIdx.x;
  const float* xr = x + (size_t)row*D_MODEL;
  float4 v = ((const float4*)xr)[tid];
  float s  = v.x+v.y+v.z+v.w;
  float s2 = v.x*v.x+v.y*v.y+v.z*v.z+v.w*v.w;
  #pragma unroll
  for (int off=1; off<64; off<<=1){ s += __shfl_xor(s,off); s2 += __shfl_xor(s2,off); }
  __shared__ float ss[4], ss2[4];
  int wave = tid>>6, lane = tid&63;
  if (lane==0){ ss[wave]=s; ss2[wave]=s2; }
  __syncthreads();
  s  = ss[0]+ss[1]+ss[2]+ss[3];
  s2 = ss2[0]+ss2[1]+ss2[2]+ss2[3];
  float mu  = s * (1.0f/D_MODEL);
  float var = s2 * (1.0f/D_MODEL) - mu*mu;
  float rstd = rsqrtf(var + 1e-5f);
  float4 wv = ((const float4*)w)[tid];
  float4 bv = ((const float4*)b)[tid];
  uint2 pk;
  pk.x = pk2bf((v.x-mu)*rstd*wv.x + bv.x, (v.y-mu)*rstd*wv.y + bv.y);
  pk.y = pk2bf((v.z-mu)*rstd*wv.z + bv.z, (v.w-mu)*rstd*wv.w + bv.w);
  *(uint2*)(out + (size_t)row*D_MODEL + tid*4) = pk;
}

// ---------------- GEMM: C[M,N] = A[M,K]bf16 * BT[N,K]bf16^T + epilogue -----
// 128 x BN tile, 4 waves (2x2). K-loop LDS pad-free, 16B chunks XOR-swizzled.
// Accumulates C^T (acc reg r -> col quad*4+r, lane l16 -> row).
// Epilogue stages C in LDS (reusing As/Bs), then writes FULL cache lines.
// MODE 0: bf16 = acc+bias (BN=128) | 1: f32 = acc+bias+res (BN=64)
// MODE 2: bf16 = gelu(acc+bias) (BN=128)
template<int MODE, int BN>
__global__ __launch_bounds__(256, 4) void gemm_bt(const ushort_t* __restrict__ A,
                                                  const ushort_t* __restrict__ BT,
                                                  const float* __restrict__ bias,
                                                  const float* __restrict__ res,
                                                  void* __restrict__ out,
                                                  int M, int N, int K){
  constexpr int NI = BN/32;        // acc frags per wave in N
  constexpr int BG = BN/32;        // B staging groups
  constexpr int KBYTES = 128*64*2 + BN*64*2;
  constexpr int CBYTES = (MODE==1) ? 64*66*4 : 128*132*2;
  constexpr int SBYTES = (KBYTES > CBYTES) ? KBYTES : CBYTES;
  __shared__ __align__(16) char smem[SBYTES];
  ushort_t* As = (ushort_t*)smem;
  ushort_t* Bs = As + 128*64;
  const int m0 = blockIdx.x*128, n0 = blockIdx.y*BN;
  const int tid = threadIdx.x;
  const int wave = tid >> 6, lane = tid & 63;
  const int wm = (wave >> 1)*64, wn = (wave & 1)*(BN/2);
  const int quad = lane >> 4, l16 = lane & 15;

  f32x4 acc[4][NI] = {};

  for (int k0 = 0; k0 < K; k0 += 64) {
    #pragma unroll
    for (int c = 0; c < 4; ++c) {
      int q   = (c*4 + wave)*64 + lane;
      int row = q >> 3, pos = q & 7;
      int lc  = pos ^ (row & 7);
      __builtin_amdgcn_global_load_lds(AS1(A + (size_t)(m0+row)*K + k0 + lc*8),
                                       AS3(&As[(c*4+wave)*512]), 16, 0, 0);
    }
    #pragma unroll
    for (int c = 0; c < BG; ++c) {
      int q   = (c*4 + wave)*64 + lane;
      int row = q >> 3, pos = q & 7;
      int lc  = pos ^ (row & 7);
      __builtin_amdgcn_global_load_lds(AS1(BT + (size_t)(n0+row)*K + k0 + lc*8),
                                       AS3(&Bs[(c*4+wave)*512]), 16, 0, 0);
    }
    __syncthreads();
    #pragma unroll
    for (int kk = 0; kk < 64; kk += 32) {
      bf16x8 af[4], bfr[NI];
      #pragma unroll
      for (int i = 0; i < 4; ++i){
        int row = wm + i*16 + l16;
        int pos = ((kk>>3) + quad) ^ (row & 7);     // kk is ELEMENT offset here
        af[i] = *(const bf16x8*)(&As[row*64 + pos*8]);
      }
      #pragma unroll
      for (int i = 0; i < NI; ++i){
        int row = wn + i*16 + l16;
        int pos = ((kk>>3) + quad) ^ (row & 7);
        bfr[i] = *(const bf16x8*)(&Bs[row*64 + pos*8]);
      }
      #pragma unroll
      for (int mi = 0; mi < 4; ++mi)
        #pragma unroll
        for (int ni = 0; ni < NI; ++ni)
          acc[mi][ni] = __builtin_amdgcn_mfma_f32_16x16x32_bf16(bfr[ni], af[mi], acc[mi][ni], 0,0,0);
    }
    __syncthreads();
  }

  if constexpr (MODE == 1) {
    // fp32 + residual: two 64-row passes through LDS (64 x 66 f32)
    float* Cf = (float*)smem;
    #pragma unroll
    for (int ph = 0; ph < 2; ++ph){
      if (ph) __syncthreads();
      if (wm == ph*64) {
        #pragma unroll
        for (int ni = 0; ni < NI; ++ni){
          int cb = wn + ni*16 + quad*4;
          float4 b4 = *(const float4*)(bias + n0 + cb);
          #pragma unroll
          for (int mi = 0; mi < 4; ++mi){
            int lm = mi*16 + l16;
            float2 v01 = make_float2(acc[mi][ni][0] + b4.x, acc[mi][ni][1] + b4.y);
            float2 v23 = make_float2(acc[mi][ni][2] + b4.z, acc[mi][ni][3] + b4.w);
            *(float2*)(&Cf[lm*66 + cb])     = v01;
            *(float2*)(&Cf[lm*66 + cb + 2]) = v23;
          }
        }
      }
      __syncthreads();
      // cooperative full-line writes: row lr, 16B chunk (jj*4 + qq)
      int lr = tid >> 2, qq = tid & 3;
      size_t grow = (size_t)(m0 + ph*64 + lr)*N + n0;
      #pragma unroll
      for (int jj = 0; jj < 4; ++jj){
        int cc = (jj*4 + qq)*4;
        float2 a  = *(float2*)(&Cf[lr*66 + cc]);
        float2 c2 = *(float2*)(&Cf[lr*66 + cc + 2]);
        float4 r4 = *(const float4*)(res + grow + cc);
        float4 o4 = make_float4(a.x + r4.x, a.y + r4.y, c2.x + r4.z, c2.y + r4.w);
        *(float4*)((float*)out + grow + cc) = o4;
      }
    }
  } else {
    // bf16: stage full 128 x 128 tile (stride 132), then full-line stores
    ushort_t* Cs = (ushort_t*)smem;
    #pragma unroll
    for (int ni = 0; ni < NI; ++ni){
      int cb = wn + ni*16 + quad*4;
      float4 b4 = *(const float4*)(bias + n0 + cb);
      #pragma unroll
      for (int mi = 0; mi < 4; ++mi){
        int m = wm + mi*16 + l16;
        float v0 = acc[mi][ni][0] + b4.x;
        float v1 = acc[mi][ni][1] + b4.y;
        float v2 = acc[mi][ni][2] + b4.z;
        float v3 = acc[mi][ni][3] + b4.w;
        if constexpr (MODE == 2){
          v0 = 0.5f*v0*(1.0f + erff(v0*0.70710678118654752f));
          v1 = 0.5f*v1*(1.0f + erff(v1*0.70710678118654752f));
          v2 = 0.5f*v2*(1.0f + erff(v2*0.70710678118654752f));
          v3 = 0.5f*v3*(1.0f + erff(v3*0.70710678118654752f));
        }
        uint2 pk; pk.x = pk2bf(v0,v1); pk.y = pk2bf(v2,v3);
        *(uint2*)(&Cs[m*132 + cb]) = pk;
      }
    }
    __syncthreads();
    int r = tid >> 1, hh2 = tid & 1;                 // row, 128B half
    size_t grow = (size_t)(m0 + r)*N + n0 + hh2*64;
    #pragma unroll
    for (int jj = 0; jj < 8; ++jj){
      uint2 a  = *(uint2*)(&Cs[r*132 + hh2*64 + jj*8]);
      uint2 b2 = *(uint2*)(&Cs[r*132 + hh2*64 + jj*8 + 4]);
      uint4 o4 = make_uint4(a.x, a.y, b2.x, b2.y);
      *(uint4*)((ushort_t*)out + grow + jj*8) = o4;
    }
  }
}

// ---------------- V transpose: qkv v-part -> vt [bh][64][T] ----------------
#define LDSS 72
__global__ __launch_bounds__(256) void vtrans(const ushort_t* __restrict__ qkv,
                                              ushort_t* __restrict__ vt){
  __shared__ __align__(16) ushort_t tile[64*LDSS];
  const int bh = blockIdx.x;
  const int b = bh >> 4, h = bh & 15;
  const int t0 = blockIdx.y*64;
  const int tid = threadIdx.x;
  #pragma unroll
  for (int it = 0; it < 2; ++it){
    int idx = it*256 + tid;
    int i = idx >> 3, c = (idx & 7) << 3;
    uint4 vv = *(const uint4*)(qkv + (size_t)(b*TSEQ + t0 + i)*3072 + 2048 + h*64 + c);
    *(uint4*)(&tile[i*LDSS + c]) = vv;
  }
  __syncthreads();
  #pragma unroll
  for (int it = 0; it < 2; ++it){
    int idx = it*256 + tid;
    int j = idx >> 3, ii = (idx & 7) << 3;
    union { unsigned short us[8]; uint4 u4; } pk;
    #pragma unroll
    for (int e = 0; e < 8; ++e) pk.us[e] = tile[(ii+e)*LDSS + j];
    *(uint4*)(vt + (size_t)(bh*64 + j)*TSEQ + t0 + ii) = pk.u4;
  }
}

// ---------------- flash attention (S^T, Q-tile 128, LDS K/V dbuf) -----------
// Block: 128 Q rows = 2 groups of 64 (wave w, group g -> rows q0+g*64+w*16+l16).
// Both groups share each staged K/V tile; g processed sequentially (P LDS
// reused within the wave). g0 skips the final tile (fully above diagonal).
#define PSTR 72
__global__ __launch_bounds__(256) void attn_kernel(const ushort_t* __restrict__ qkv,
                                                   const ushort_t* __restrict__ vt,
                                                   ushort_t* __restrict__ y){
  __shared__ __align__(16) ushort_t Ks[2][64*64];
  __shared__ __align__(16) ushort_t Vs[2][64*64];
  __shared__ __align__(16) ushort_t Plds[4][16*PSTR];
  const int bh = blockIdx.x;
  const int b = bh >> 4, h = bh & 15;
  const int qt = (TSEQ/128 - 1) - blockIdx.y;      // heavy tiles first (LPT)
  const int q0 = qt * 128;
  const int wave = threadIdx.x >> 6, lane = threadIdx.x & 63;
  const int quad = lane >> 4, l16 = lane & 15;

  const ushort_t* qbase = qkv + (size_t)(b*TSEQ)*3072 + h*64;
  const ushort_t* kbase = qbase + 1024;
  const ushort_t* vbase = vt + (size_t)(bh*64)*TSEQ;
  ushort_t* P = Plds[wave];

  auto stage = [&](int buf, int j0){
    #pragma unroll
    for (int c = 0; c < 2; ++c){
      int q = (wave*2 + c)*64 + lane;
      int row = q >> 3, pos = q & 7;
      int lc = pos ^ (row & 7);
      __builtin_amdgcn_global_load_lds(AS1(kbase + (size_t)(j0+row)*3072 + lc*8),
                                       AS3(&Ks[buf][(wave*2+c)*512]), 16, 0, 0);
      __builtin_amdgcn_global_load_lds(AS1(vbase + (size_t)row*TSEQ + j0 + lc*8),
                                       AS3(&Vs[buf][(wave*2+c)*512]), 16, 0, 0);
    }
  };

  int qrow[2];
  bf16x8 qf[2][2];
  #pragma unroll
  for (int g = 0; g < 2; ++g){
    qrow[g] = q0 + g*64 + wave*16 + l16;
    #pragma unroll
    for (int kk = 0; kk < 2; ++kk)
      qf[g][kk] = *(const bf16x8*)(qbase + (size_t)qrow[g]*3072 + kk*32 + quad*8);
  }

  float m_i[2] = {-3e38f, -3e38f}, l_i[2] = {0.f, 0.f};
  f32x4 o[2][4] = {};
  const float cs = 0.18033688011112042f;           // (1/8) * log2(e)

  const int ntiles = 2*qt + 2;
  stage(0, 0);
  for (int it = 0; it < ntiles; ++it) {
    const int cur = it & 1;
    const int j0 = it * 64;
    __syncthreads();                               // staged buf `cur` ready
    if (it + 1 < ntiles) stage(cur ^ 1, j0 + 64);
    #pragma unroll
    for (int g = 0; g < 2; ++g){
      if (g == 0 && it == ntiles-1) continue;      // fully masked for g0
      // --- S^T = K . Q^T : rows j, col m=l16 ---
      f32x4 s[4] = {};
      #pragma unroll
      for (int kk = 0; kk < 2; ++kk){
        #pragma unroll
        for (int nj = 0; nj < 4; ++nj){
          int row = nj*16 + l16;
          int pos = (kk*4 + quad) ^ (row & 7);
          bf16x8 kf = *(const bf16x8*)(&Ks[cur][row*64 + pos*8]);
          s[nj] = __builtin_amdgcn_mfma_f32_16x16x32_bf16(kf, qf[g][kk], s[nj], 0,0,0);
        }
      }
      if (it >= ntiles-2) {                        // diagonal region: mask
        #pragma unroll
        for (int nj = 0; nj < 4; ++nj)
          #pragma unroll
          for (int r = 0; r < 4; ++r){
            int jc = j0 + nj*16 + quad*4 + r;
            if (jc > qrow[g]) s[nj][r] = -3e38f;
          }
      }
      float mloc = s[0][0];
      #pragma unroll
      for (int nj = 0; nj < 4; ++nj)
        #pragma unroll
        for (int r = 0; r < 4; ++r) mloc = fmaxf(mloc, s[nj][r]);
      mloc = fmaxf(mloc, __shfl_xor(mloc, 16));
      mloc = fmaxf(mloc, __shfl_xor(mloc, 32));
      float mn = fmaxf(m_i[g], mloc);
      float alpha = __builtin_amdgcn_exp2f((m_i[g] - mn)*cs);
      m_i[g] = mn;
      float rs = 0.f;
      #pragma unroll
      for (int nj = 0; nj < 4; ++nj){
        float p0 = __builtin_amdgcn_exp2f((s[nj][0]-mn)*cs);
        float p1 = __builtin_amdgcn_exp2f((s[nj][1]-mn)*cs);
        float p2 = __builtin_amdgcn_exp2f((s[nj][2]-mn)*cs);
        float p3 = __builtin_amdgcn_exp2f((s[nj][3]-mn)*cs);
        rs += (p0+p1)+(p2+p3);
        uint2 pk; pk.x = pk2bf(p0,p1); pk.y = pk2bf(p2,p3);
        *(uint2*)(&P[l16*PSTR + nj*16 + quad*4]) = pk;   // P^T[m][j]
      }
      rs += __shfl_xor(rs, 16);
      rs += __shfl_xor(rs, 32);
      l_i[g] = l_i[g]*alpha + rs;
      #pragma unroll
      for (int dj = 0; dj < 4; ++dj)
        #pragma unroll
        for (int r = 0; r < 4; ++r) o[g][dj][r] *= alpha;
      // --- O^T += V^T . P^T ---
      bf16x8 pf[2];
      #pragma unroll
      for (int kk = 0; kk < 2; ++kk)
        pf[kk] = *(const bf16x8*)(&P[l16*PSTR + kk*32 + quad*8]);
      #pragma unroll
      for (int kk = 0; kk < 2; ++kk){
        #pragma unroll
        for (int dj = 0; dj < 4; ++dj){
          int row = dj*16 + l16;
          int pos = (kk*4 + quad) ^ (row & 7);
          bf16x8 vf = *(const bf16x8*)(&Vs[cur][row*64 + pos*8]);
          o[g][dj] = __builtin_amdgcn_mfma_f32_16x16x32_bf16(vf, pf[kk], o[g][dj], 0,0,0);
        }
      }
    }
  }
  #pragma unroll
  for (int g = 0; g < 2; ++g){
    float inv = 1.0f / l_i[g];
    ushort_t* yr = y + (size_t)(b*TSEQ + qrow[g])*D_MODEL + h*64;
    #pragma unroll
    for (int dj = 0; dj < 4; ++dj){
      uint2 pk;
      pk.x = pk2bf(o[g][dj][0]*inv, o[g][dj][1]*inv);
      pk.y = pk2bf(o[g][dj][2]*inv, o[g][dj][3]*inv);
      *(uint2*)(yr + dj*16 + quad*4) = pk;
    }
  }
}

// ---------------- launcher --------------------------------------------------
extern "C" void kernel_launch(void* const* d_in, const int* in_sizes, int n_in,
                              void* d_out, int out_size, void* d_ws, size_t ws_size,
                              hipStream_t stream)
{
  (void)in_sizes; (void)n_in; (void)out_size; (void)ws_size;
  const float* x      = (const float*)d_in[0];
  const float* ln1_w  = (const float*)d_in[1];
  const float* ln1_b  = (const float*)d_in[2];
  const float* ln2_w  = (const float*)d_in[3];
  const float* ln2_b  = (const float*)d_in[4];
  const float* w_attn = (const float*)d_in[5];
  const float* b_attn = (const float*)d_in[6];
  const float* w_proj = (const float*)d_in[7];
  const float* b_proj = (const float*)d_in[8];
  const float* w_fc   = (const float*)d_in[9];
  const float* b_fc   = (const float*)d_in[10];
  const float* w_fc2  = (const float*)d_in[11];
  const float* b_fc2  = (const float*)d_in[12];
  float* out = (float*)d_out;

  char* p = (char*)d_ws;
  auto alloc = [&](size_t n){ char* r = p; p += (n + 255) & ~(size_t)255; return (void*)r; };
  ushort_t* wAT  = (ushort_t*)alloc((size_t)3072*1024*2);
  ushort_t* wPT  = (ushort_t*)alloc((size_t)1024*1024*2);
  ushort_t* wFT  = (ushort_t*)alloc((size_t)4096*1024*2);
  ushort_t* wF2T = (ushort_t*)alloc((size_t)1024*4096*2);
  ushort_t* hbuf = (ushort_t*)alloc((size_t)NTOK*D_MODEL*2);
  ushort_t* qkv  = (ushort_t*)alloc((size_t)NTOK*4096*2);   // qkv, later fc1 out
  ushort_t* vt   = (ushort_t*)alloc((size_t)32*64*TSEQ*2);
  ushort_t* ybuf = (ushort_t*)alloc((size_t)NTOK*D_MODEL*2);
  float*    x1   = (float*)   alloc((size_t)NTOK*D_MODEL*4);
  ushort_t* hh   = qkv;

  wtrans_all<<<12288, 256, 0, stream>>>(w_attn, wAT, w_proj, wPT, w_fc, wFT, w_fc2, wF2T);

  ln_kernel<<<NTOK, 256, 0, stream>>>(x, ln1_w, ln1_b, hbuf);
  gemm_bt<0,128><<<dim3(NTOK/128, 3072/128), 256, 0, stream>>>(hbuf, wAT, b_attn, nullptr, qkv, NTOK, 3072, 1024);
  vtrans<<<dim3(32, TSEQ/64), 256, 0, stream>>>(qkv, vt);
  attn_kernel<<<dim3(32, TSEQ/128), 256, 0, stream>>>(qkv, vt, ybuf);
  gemm_bt<1,64><<<dim3(NTOK/128, 1024/64), 256, 0, stream>>>(ybuf, wPT, b_proj, x, x1, NTOK, 1024, 1024);
  ln_kernel<<<NTOK, 256, 0, stream>>>(x1, ln2_w, ln2_b, hbuf);
  gemm_bt<2,128><<<dim3(NTOK/128, 4096/128), 256, 0, stream>>>(hbuf, wFT, b_fc, nullptr, hh, NTOK, 4096, 1024);
  gemm_bt<1,64><<<dim3(NTOK/128, 1024/64), 256, 0, stream>>>(hh, wF2T, b_fc2, x1, out, NTOK, 1024, 4096);
}

// Round 7
// 359.558 us; speedup vs baseline: 1.0333x; 1.0333x over previous
//
#include <hip/hip_runtime.h>
#include <cstdint>
#include <cstddef>

// TransformerBlock on MI355X (gfx950). bf16 MFMA everywhere, fp32 spine.
// R7: attention causal work-pairing — block (bh, i) handles Q-tiles qtA=i and
//     qtB=31-i (64 rows each): per-block compute = 33 j-tiles CONSTANT (R6
//     counter evidence: occupancy 12% from block-runtime variance 2..32).
//     Shared K/V staging (A's j-range is a prefix of B's). GEMM/LN unchanged.

#define D_MODEL 1024
#define TSEQ    2048
#define BATCH   2
#define NHEADS  16
#define NTOK    (BATCH*TSEQ)   // 4096

typedef __attribute__((ext_vector_type(8))) short bf16x8;
typedef __attribute__((ext_vector_type(4))) float f32x4;
typedef unsigned short ushort_t;

#define AS3(p) ((__attribute__((address_space(3))) unsigned int*)(p))
#define AS1(p) ((const __attribute__((address_space(1))) unsigned int*)(p))

__device__ __forceinline__ unsigned short f2bf(float f){
  union { float f; unsigned u; } v; v.f = f;
  unsigned r = v.u + 0x7fffu + ((v.u >> 16) & 1u);
  return (unsigned short)(r >> 16);
}
__device__ __forceinline__ unsigned pk2bf(float a, float b){
  union { float f; unsigned u; } x, y; x.f = a; y.f = b;
  return __builtin_amdgcn_perm(y.u + 0x8000u, x.u + 0x8000u, 0x07060302u);
}

// ------------- fused weight convert+transpose: fp32 [K][N] -> bf16 [N][K] ---
__global__ __launch_bounds__(256) void wtrans_all(
    const float* __restrict__ w0, ushort_t* __restrict__ o0,
    const float* __restrict__ w1, ushort_t* __restrict__ o1,
    const float* __restrict__ w2, ushort_t* __restrict__ o2,
    const float* __restrict__ w3, ushort_t* __restrict__ o3){
  __shared__ float tile[32][33];
  int bid = blockIdx.x;
  const float* in; ushort_t* out; int K, N, t;
  if (bid < 3072)      { in=w0; out=o0; K=1024; N=3072; t=bid; }
  else if (bid < 4096) { in=w1; out=o1; K=1024; N=1024; t=bid-3072; }
  else if (bid < 8192) { in=w2; out=o2; K=1024; N=4096; t=bid-4096; }
  else                 { in=w3; out=o3; K=4096; N=1024; t=bid-8192; }
  int tx_n = N >> 5;
  int n0 = (t % tx_n)*32, k0 = (t / tx_n)*32;
  int tx = threadIdx.x & 31, ty = threadIdx.x >> 5;   // 32 x 8
  #pragma unroll
  for (int i=0;i<32;i+=8)
    tile[ty+i][tx] = in[(size_t)(k0+ty+i)*N + n0+tx];
  __syncthreads();
  #pragma unroll
  for (int i=0;i<32;i+=8)
    out[(size_t)(n0+ty+i)*K + k0+tx] = f2bf(tile[tx][ty+i]);
}

// ---------------- layernorm: fp32 row[1024] -> bf16 ------------------------
__global__ __launch_bounds__(256) void ln_kernel(const float* __restrict__ x,
                                                 const float* __restrict__ w,
                                                 const float* __restrict__ b,
                                                 ushort_t* __restrict__ out){
  int row = blockIdx.x;
  int tid = threadIdx.x;
  const float* xr = x + (size_t)row*D_MODEL;
  float4 v = ((const float4*)xr)[tid];
  float s  = v.x+v.y+v.z+v.w;
  float s2 = v.x*v.x+v.y*v.y+v.z*v.z+v.w*v.w;
  #pragma unroll
  for (int off=1; off<64; off<<=1){ s += __shfl_xor(s,off); s2 += __shfl_xor(s2,off); }
  __shared__ float ss[4], ss2[4];
  int wave = tid>>6, lane = tid&63;
  if (lane==0){ ss[wave]=s; ss2[wave]=s2; }
  __syncthreads();
  s  = ss[0]+ss[1]+ss[2]+ss[3];
  s2 = ss2[0]+ss2[1]+ss2[2]+ss2[3];
  float mu  = s * (1.0f/D_MODEL);
  float var = s2 * (1.0f/D_MODEL) - mu*mu;
  float rstd = rsqrtf(var + 1e-5f);
  float4 wv = ((const float4*)w)[tid];
  float4 bv = ((const float4*)b)[tid];
  uint2 pk;
  pk.x = pk2bf((v.x-mu)*rstd*wv.x + bv.x, (v.y-mu)*rstd*wv.y + bv.y);
  pk.y = pk2bf((v.z-mu)*rstd*wv.z + bv.z, (v.w-mu)*rstd*wv.w + bv.w);
  *(uint2*)(out + (size_t)row*D_MODEL + tid*4) = pk;
}

// ---------------- GEMM: C[M,N] = A[M,K]bf16 * BT[N,K]bf16^T + epilogue -----
// 128 x BN tile, 4 waves (2x2). K-loop LDS pad-free, 16B chunks XOR-swizzled.
// Accumulates C^T (acc reg r -> col quad*4+r, lane l16 -> row).
// Epilogue stages C in LDS (reusing As/Bs), then writes FULL cache lines.
// MODE 0: bf16 = acc+bias (BN=128) | 1: f32 = acc+bias+res (BN=64)
// MODE 2: bf16 = gelu(acc+bias) (BN=128)
template<int MODE, int BN>
__global__ __launch_bounds__(256, 4) void gemm_bt(const ushort_t* __restrict__ A,
                                                  const ushort_t* __restrict__ BT,
                                                  const float* __restrict__ bias,
                                                  const float* __restrict__ res,
                                                  void* __restrict__ out,
                                                  int M, int N, int K){
  constexpr int NI = BN/32;        // acc frags per wave in N
  constexpr int BG = BN/32;        // B staging groups
  constexpr int KBYTES = 128*64*2 + BN*64*2;
  constexpr int CBYTES = (MODE==1) ? 64*66*4 : 128*132*2;
  constexpr int SBYTES = (KBYTES > CBYTES) ? KBYTES : CBYTES;
  __shared__ __align__(16) char smem[SBYTES];
  ushort_t* As = (ushort_t*)smem;
  ushort_t* Bs = As + 128*64;
  const int m0 = blockIdx.x*128, n0 = blockIdx.y*BN;
  const int tid = threadIdx.x;
  const int wave = tid >> 6, lane = tid & 63;
  const int wm = (wave >> 1)*64, wn = (wave & 1)*(BN/2);
  const int quad = lane >> 4, l16 = lane & 15;

  f32x4 acc[4][NI] = {};

  for (int k0 = 0; k0 < K; k0 += 64) {
    #pragma unroll
    for (int c = 0; c < 4; ++c) {
      int q   = (c*4 + wave)*64 + lane;
      int row = q >> 3, pos = q & 7;
      int lc  = pos ^ (row & 7);
      __builtin_amdgcn_global_load_lds(AS1(A + (size_t)(m0+row)*K + k0 + lc*8),
                                       AS3(&As[(c*4+wave)*512]), 16, 0, 0);
    }
    #pragma unroll
    for (int c = 0; c < BG; ++c) {
      int q   = (c*4 + wave)*64 + lane;
      int row = q >> 3, pos = q & 7;
      int lc  = pos ^ (row & 7);
      __builtin_amdgcn_global_load_lds(AS1(BT + (size_t)(n0+row)*K + k0 + lc*8),
                                       AS3(&Bs[(c*4+wave)*512]), 16, 0, 0);
    }
    __syncthreads();
    #pragma unroll
    for (int kk = 0; kk < 64; kk += 32) {
      bf16x8 af[4], bfr[NI];
      #pragma unroll
      for (int i = 0; i < 4; ++i){
        int row = wm + i*16 + l16;
        int pos = ((kk>>3) + quad) ^ (row & 7);     // kk is ELEMENT offset here
        af[i] = *(const bf16x8*)(&As[row*64 + pos*8]);
      }
      #pragma unroll
      for (int i = 0; i < NI; ++i){
        int row = wn + i*16 + l16;
        int pos = ((kk>>3) + quad) ^ (row & 7);
        bfr[i] = *(const bf16x8*)(&Bs[row*64 + pos*8]);
      }
      #pragma unroll
      for (int mi = 0; mi < 4; ++mi)
        #pragma unroll
        for (int ni = 0; ni < NI; ++ni)
          acc[mi][ni] = __builtin_amdgcn_mfma_f32_16x16x32_bf16(bfr[ni], af[mi], acc[mi][ni], 0,0,0);
    }
    __syncthreads();
  }

  if constexpr (MODE == 1) {
    // fp32 + residual: two 64-row passes through LDS (64 x 66 f32)
    float* Cf = (float*)smem;
    #pragma unroll
    for (int ph = 0; ph < 2; ++ph){
      if (ph) __syncthreads();
      if (wm == ph*64) {
        #pragma unroll
        for (int ni = 0; ni < NI; ++ni){
          int cb = wn + ni*16 + quad*4;
          float4 b4 = *(const float4*)(bias + n0 + cb);
          #pragma unroll
          for (int mi = 0; mi < 4; ++mi){
            int lm = mi*16 + l16;
            float2 v01 = make_float2(acc[mi][ni][0] + b4.x, acc[mi][ni][1] + b4.y);
            float2 v23 = make_float2(acc[mi][ni][2] + b4.z, acc[mi][ni][3] + b4.w);
            *(float2*)(&Cf[lm*66 + cb])     = v01;
            *(float2*)(&Cf[lm*66 + cb + 2]) = v23;
          }
        }
      }
      __syncthreads();
      // cooperative full-line writes: row lr, 16B chunk (jj*4 + qq)
      int lr = tid >> 2, qq = tid & 3;
      size_t grow = (size_t)(m0 + ph*64 + lr)*N + n0;
      #pragma unroll
      for (int jj = 0; jj < 4; ++jj){
        int cc = (jj*4 + qq)*4;
        float2 a  = *(float2*)(&Cf[lr*66 + cc]);
        float2 c2 = *(float2*)(&Cf[lr*66 + cc + 2]);
        float4 r4 = *(const float4*)(res + grow + cc);
        float4 o4 = make_float4(a.x + r4.x, a.y + r4.y, c2.x + r4.z, c2.y + r4.w);
        *(float4*)((float*)out + grow + cc) = o4;
      }
    }
  } else {
    // bf16: stage full 128 x 128 tile (stride 132), then full-line stores
    ushort_t* Cs = (ushort_t*)smem;
    #pragma unroll
    for (int ni = 0; ni < NI; ++ni){
      int cb = wn + ni*16 + quad*4;
      float4 b4 = *(const float4*)(bias + n0 + cb);
      #pragma unroll
      for (int mi = 0; mi < 4; ++mi){
        int m = wm + mi*16 + l16;
        float v0 = acc[mi][ni][0] + b4.x;
        float v1 = acc[mi][ni][1] + b4.y;
        float v2 = acc[mi][ni][2] + b4.z;
        float v3 = acc[mi][ni][3] + b4.w;
        if constexpr (MODE == 2){
          v0 = 0.5f*v0*(1.0f + erff(v0*0.70710678118654752f));
          v1 = 0.5f*v1*(1.0f + erff(v1*0.70710678118654752f));
          v2 = 0.5f*v2*(1.0f + erff(v2*0.70710678118654752f));
          v3 = 0.5f*v3*(1.0f + erff(v3*0.70710678118654752f));
        }
        uint2 pk; pk.x = pk2bf(v0,v1); pk.y = pk2bf(v2,v3);
        *(uint2*)(&Cs[m*132 + cb]) = pk;
      }
    }
    __syncthreads();
    int r = tid >> 1, hh2 = tid & 1;                 // row, 128B half
    size_t grow = (size_t)(m0 + r)*N + n0 + hh2*64;
    #pragma unroll
    for (int jj = 0; jj < 8; ++jj){
      uint2 a  = *(uint2*)(&Cs[r*132 + hh2*64 + jj*8]);
      uint2 b2 = *(uint2*)(&Cs[r*132 + hh2*64 + jj*8 + 4]);
      uint4 o4 = make_uint4(a.x, a.y, b2.x, b2.y);
      *(uint4*)((ushort_t*)out + grow + jj*8) = o4;
    }
  }
}

// ---------------- V transpose: qkv v-part -> vt [bh][64][T] ----------------
#define LDSS 72
__global__ __launch_bounds__(256) void vtrans(const ushort_t* __restrict__ qkv,
                                              ushort_t* __restrict__ vt){
  __shared__ __align__(16) ushort_t tile[64*LDSS];
  const int bh = blockIdx.x;
  const int b = bh >> 4, h = bh & 15;
  const int t0 = blockIdx.y*64;
  const int tid = threadIdx.x;
  #pragma unroll
  for (int it = 0; it < 2; ++it){
    int idx = it*256 + tid;
    int i = idx >> 3, c = (idx & 7) << 3;
    uint4 vv = *(const uint4*)(qkv + (size_t)(b*TSEQ + t0 + i)*3072 + 2048 + h*64 + c);
    *(uint4*)(&tile[i*LDSS + c]) = vv;
  }
  __syncthreads();
  #pragma unroll
  for (int it = 0; it < 2; ++it){
    int idx = it*256 + tid;
    int j = idx >> 3, ii = (idx & 7) << 3;
    union { unsigned short us[8]; uint4 u4; } pk;
    #pragma unroll
    for (int e = 0; e < 8; ++e) pk.us[e] = tile[(ii+e)*LDSS + j];
    *(uint4*)(vt + (size_t)(bh*64 + j)*TSEQ + t0 + ii) = pk.u4;
  }
}

// ---------------- flash attention (S^T, paired Q-tiles, LDS K/V dbuf) -------
// Block (bh, i): Q-tiles qtA=i (rows qtA*64..) and qtB=31-i. Work per block =
// (qtA+1)+(qtB+1) = 33 j-tiles, constant across the grid (causal balancing).
// A's j-range is a prefix of B's, so both share each staged K/V tile.
#define PSTR 72
__global__ __launch_bounds__(256) void attn_kernel(const ushort_t* __restrict__ qkv,
                                                   const ushort_t* __restrict__ vt,
                                                   ushort_t* __restrict__ y){
  __shared__ __align__(16) ushort_t Ks[2][64*64];
  __shared__ __align__(16) ushort_t Vs[2][64*64];
  __shared__ __align__(16) ushort_t Plds[4][16*PSTR];
  const int bh = blockIdx.x;
  const int b = bh >> 4, h = bh & 15;
  const int qtA = blockIdx.y;                      // 0..15
  const int qtB = (TSEQ/64 - 1) - qtA;             // 31..16
  const int wave = threadIdx.x >> 6, lane = threadIdx.x & 63;
  const int quad = lane >> 4, l16 = lane & 15;

  const ushort_t* qbase = qkv + (size_t)(b*TSEQ)*3072 + h*64;
  const ushort_t* kbase = qbase + 1024;
  const ushort_t* vbase = vt + (size_t)(bh*64)*TSEQ;
  ushort_t* P = Plds[wave];

  auto stage = [&](int buf, int j0){
    #pragma unroll
    for (int c = 0; c < 2; ++c){
      int q = (wave*2 + c)*64 + lane;
      int row = q >> 3, pos = q & 7;
      int lc = pos ^ (row & 7);
      __builtin_amdgcn_global_load_lds(AS1(kbase + (size_t)(j0+row)*3072 + lc*8),
                                       AS3(&Ks[buf][(wave*2+c)*512]), 16, 0, 0);
      __builtin_amdgcn_global_load_lds(AS1(vbase + (size_t)row*TSEQ + j0 + lc*8),
                                       AS3(&Vs[buf][(wave*2+c)*512]), 16, 0, 0);
    }
  };

  const int qtg[2] = {qtA, qtB};
  int qrow[2];
  bf16x8 qf[2][2];
  #pragma unroll
  for (int g = 0; g < 2; ++g){
    qrow[g] = qtg[g]*64 + wave*16 + l16;
    #pragma unroll
    for (int kk = 0; kk < 2; ++kk)
      qf[g][kk] = *(const bf16x8*)(qbase + (size_t)qrow[g]*3072 + kk*32 + quad*8);
  }

  float m_i[2] = {-3e38f, -3e38f}, l_i[2] = {0.f, 0.f};
  f32x4 o[2][4] = {};
  const float cs = 0.18033688011112042f;           // (1/8) * log2(e)

  const int ntiles = qtB + 1;                      // B's j-range (superset)
  stage(0, 0);
  for (int it = 0; it < ntiles; ++it) {
    const int cur = it & 1;
    const int j0 = it * 64;
    __syncthreads();                               // staged buf `cur` ready
    if (it + 1 < ntiles) stage(cur ^ 1, j0 + 64);
    #pragma unroll
    for (int g = 0; g < 2; ++g){
      if (g == 0 && it > qtA) continue;            // A done past its diagonal
      // --- S^T = K . Q^T : rows j, col m=l16 ---
      f32x4 s[4] = {};
      #pragma unroll
      for (int kk = 0; kk < 2; ++kk){
        #pragma unroll
        for (int nj = 0; nj < 4; ++nj){
          int row = nj*16 + l16;
          int pos = (kk*4 + quad) ^ (row & 7);
          bf16x8 kf = *(const bf16x8*)(&Ks[cur][row*64 + pos*8]);
          s[nj] = __builtin_amdgcn_mfma_f32_16x16x32_bf16(kf, qf[g][kk], s[nj], 0,0,0);
        }
      }
      if (it == qtg[g]) {                          // this group's diagonal tile
        #pragma unroll
        for (int nj = 0; nj < 4; ++nj)
          #pragma unroll
          for (int r = 0; r < 4; ++r){
            int jc = j0 + nj*16 + quad*4 + r;
            if (jc > qrow[g]) s[nj][r] = -3e38f;
          }
      }
      float mloc = s[0][0];
      #pragma unroll
      for (int nj = 0; nj < 4; ++nj)
        #pragma unroll
        for (int r = 0; r < 4; ++r) mloc = fmaxf(mloc, s[nj][r]);
      mloc = fmaxf(mloc, __shfl_xor(mloc, 16));
      mloc = fmaxf(mloc, __shfl_xor(mloc, 32));
      float mn = fmaxf(m_i[g], mloc);
      float alpha = __builtin_amdgcn_exp2f((m_i[g] - mn)*cs);
      m_i[g] = mn;
      float rs = 0.f;
      #pragma unroll
      for (int nj = 0; nj < 4; ++nj){
        float p0 = __builtin_amdgcn_exp2f((s[nj][0]-mn)*cs);
        float p1 = __builtin_amdgcn_exp2f((s[nj][1]-mn)*cs);
        float p2 = __builtin_amdgcn_exp2f((s[nj][2]-mn)*cs);
        float p3 = __builtin_amdgcn_exp2f((s[nj][3]-mn)*cs);
        rs += (p0+p1)+(p2+p3);
        uint2 pk; pk.x = pk2bf(p0,p1); pk.y = pk2bf(p2,p3);
        *(uint2*)(&P[l16*PSTR + nj*16 + quad*4]) = pk;   // P^T[m][j]
      }
      rs += __shfl_xor(rs, 16);
      rs += __shfl_xor(rs, 32);
      l_i[g] = l_i[g]*alpha + rs;
      #pragma unroll
      for (int dj = 0; dj < 4; ++dj)
        #pragma unroll
        for (int r = 0; r < 4; ++r) o[g][dj][r] *= alpha;
      // --- O^T += V^T . P^T ---
      bf16x8 pf[2];
      #pragma unroll
      for (int kk = 0; kk < 2; ++kk)
        pf[kk] = *(const bf16x8*)(&P[l16*PSTR + kk*32 + quad*8]);
      #pragma unroll
      for (int kk = 0; kk < 2; ++kk){
        #pragma unroll
        for (int dj = 0; dj < 4; ++dj){
          int row = dj*16 + l16;
          int pos = (kk*4 + quad) ^ (row & 7);
          bf16x8 vf = *(const bf16x8*)(&Vs[cur][row*64 + pos*8]);
          o[g][dj] = __builtin_amdgcn_mfma_f32_16x16x32_bf16(vf, pf[kk], o[g][dj], 0,0,0);
        }
      }
    }
  }
  #pragma unroll
  for (int g = 0; g < 2; ++g){
    float inv = 1.0f / l_i[g];
    ushort_t* yr = y + (size_t)(b*TSEQ + qrow[g])*D_MODEL + h*64;
    #pragma unroll
    for (int dj = 0; dj < 4; ++dj){
      uint2 pk;
      pk.x = pk2bf(o[g][dj][0]*inv, o[g][dj][1]*inv);
      pk.y = pk2bf(o[g][dj][2]*inv, o[g][dj][3]*inv);
      *(uint2*)(yr + dj*16 + quad*4) = pk;
    }
  }
}

// ---------------- launcher --------------------------------------------------
extern "C" void kernel_launch(void* const* d_in, const int* in_sizes, int n_in,
                              void* d_out, int out_size, void* d_ws, size_t ws_size,
                              hipStream_t stream)
{
  (void)in_sizes; (void)n_in; (void)out_size; (void)ws_size;
  const float* x      = (const float*)d_in[0];
  const float* ln1_w  = (const float*)d_in[1];
  const float* ln1_b  = (const float*)d_in[2];
  const float* ln2_w  = (const float*)d_in[3];
  const float* ln2_b  = (const float*)d_in[4];
  const float* w_attn = (const float*)d_in[5];
  const float* b_attn = (const float*)d_in[6];
  const float* w_proj = (const float*)d_in[7];
  const float* b_proj = (const float*)d_in[8];
  const float* w_fc   = (const float*)d_in[9];
  const float* b_fc   = (const float*)d_in[10];
  const float* w_fc2  = (const float*)d_in[11];
  const float* b_fc2  = (const float*)d_in[12];
  float* out = (float*)d_out;

  char* p = (char*)d_ws;
  auto alloc = [&](size_t n){ char* r = p; p += (n + 255) & ~(size_t)255; return (void*)r; };
  ushort_t* wAT  = (ushort_t*)alloc((size_t)3072*1024*2);
  ushort_t* wPT  = (ushort_t*)alloc((size_t)1024*1024*2);
  ushort_t* wFT  = (ushort_t*)alloc((size_t)4096*1024*2);
  ushort_t* wF2T = (ushort_t*)alloc((size_t)1024*4096*2);
  ushort_t* hbuf = (ushort_t*)alloc((size_t)NTOK*D_MODEL*2);
  ushort_t* qkv  = (ushort_t*)alloc((size_t)NTOK*4096*2);   // qkv, later fc1 out
  ushort_t* vt   = (ushort_t*)alloc((size_t)32*64*TSEQ*2);
  ushort_t* ybuf = (ushort_t*)alloc((size_t)NTOK*D_MODEL*2);
  float*    x1   = (float*)   alloc((size_t)NTOK*D_MODEL*4);
  ushort_t* hh   = qkv;

  wtrans_all<<<12288, 256, 0, stream>>>(w_attn, wAT, w_proj, wPT, w_fc, wFT, w_fc2, wF2T);

  ln_kernel<<<NTOK, 256, 0, stream>>>(x, ln1_w, ln1_b, hbuf);
  gemm_bt<0,128><<<dim3(NTOK/128, 3072/128), 256, 0, stream>>>(hbuf, wAT, b_attn, nullptr, qkv, NTOK, 3072, 1024);
  vtrans<<<dim3(32, TSEQ/64), 256, 0, stream>>>(qkv, vt);
  attn_kernel<<<dim3(32, TSEQ/128), 256, 0, stream>>>(qkv, vt, ybuf);
  gemm_bt<1,64><<<dim3(NTOK/128, 1024/64), 256, 0, stream>>>(ybuf, wPT, b_proj, x, x1, NTOK, 1024, 1024);
  ln_kernel<<<NTOK, 256, 0, stream>>>(x1, ln2_w, ln2_b, hbuf);
  gemm_bt<2,128><<<dim3(NTOK/128, 4096/128), 256, 0, stream>>>(hbuf, wFT, b_fc, nullptr, hh, NTOK, 4096, 1024);
  gemm_bt<1,64><<<dim3(NTOK/128, 1024/64), 256, 0, stream>>>(hh, wF2T, b_fc2, x1, out, NTOK, 1024, 4096);
}

// Round 8
// 330.540 us; speedup vs baseline: 1.1240x; 1.0878x over previous
//
#include <hip/hip_runtime.h>
#include <cstdint>
#include <cstddef>

// TransformerBlock on MI355X (gfx950). bf16 MFMA everywhere, fp32 spine.
// R8: MODE=1 GEMMs (proj, FC2) use BK=128 — R7 counters show FC2 is
//     barrier-latency-bound (MfmaUtil 20%, VALU 10%, HBM 15%, grid-capped at
//     2 blocks/CU): doubling K-tile halves barrier count at zero occupancy
//     cost (49KB LDS x 2 blocks = 98KB < 160KB). QKV/FC1 stay BK=64 (they
//     run 3-4 blocks/CU; 64KB LDS would cut residency — m132 lesson).

#define D_MODEL 1024
#define TSEQ    2048
#define BATCH   2
#define NHEADS  16
#define NTOK    (BATCH*TSEQ)   // 4096

typedef __attribute__((ext_vector_type(8))) short bf16x8;
typedef __attribute__((ext_vector_type(4))) float f32x4;
typedef unsigned short ushort_t;

#define AS3(p) ((__attribute__((address_space(3))) unsigned int*)(p))
#define AS1(p) ((const __attribute__((address_space(1))) unsigned int*)(p))

__device__ __forceinline__ unsigned short f2bf(float f){
  union { float f; unsigned u; } v; v.f = f;
  unsigned r = v.u + 0x7fffu + ((v.u >> 16) & 1u);
  return (unsigned short)(r >> 16);
}
__device__ __forceinline__ unsigned pk2bf(float a, float b){
  union { float f; unsigned u; } x, y; x.f = a; y.f = b;
  return __builtin_amdgcn_perm(y.u + 0x8000u, x.u + 0x8000u, 0x07060302u);
}

// ------------- fused weight convert+transpose: fp32 [K][N] -> bf16 [N][K] ---
__global__ __launch_bounds__(256) void wtrans_all(
    const float* __restrict__ w0, ushort_t* __restrict__ o0,
    const float* __restrict__ w1, ushort_t* __restrict__ o1,
    const float* __restrict__ w2, ushort_t* __restrict__ o2,
    const float* __restrict__ w3, ushort_t* __restrict__ o3){
  __shared__ float tile[32][33];
  int bid = blockIdx.x;
  const float* in; ushort_t* out; int K, N, t;
  if (bid < 3072)      { in=w0; out=o0; K=1024; N=3072; t=bid; }
  else if (bid < 4096) { in=w1; out=o1; K=1024; N=1024; t=bid-3072; }
  else if (bid < 8192) { in=w2; out=o2; K=1024; N=4096; t=bid-4096; }
  else                 { in=w3; out=o3; K=4096; N=1024; t=bid-8192; }
  int tx_n = N >> 5;
  int n0 = (t % tx_n)*32, k0 = (t / tx_n)*32;
  int tx = threadIdx.x & 31, ty = threadIdx.x >> 5;   // 32 x 8
  #pragma unroll
  for (int i=0;i<32;i+=8)
    tile[ty+i][tx] = in[(size_t)(k0+ty+i)*N + n0+tx];
  __syncthreads();
  #pragma unroll
  for (int i=0;i<32;i+=8)
    out[(size_t)(n0+ty+i)*K + k0+tx] = f2bf(tile[tx][ty+i]);
}

// ---------------- layernorm: fp32 row[1024] -> bf16 ------------------------
__global__ __launch_bounds__(256) void ln_kernel(const float* __restrict__ x,
                                                 const float* __restrict__ w,
                                                 const float* __restrict__ b,
                                                 ushort_t* __restrict__ out){
  int row = blockIdx.x;
  int tid = threadIdx.x;
  const float* xr = x + (size_t)row*D_MODEL;
  float4 v = ((const float4*)xr)[tid];
  float s  = v.x+v.y+v.z+v.w;
  float s2 = v.x*v.x+v.y*v.y+v.z*v.z+v.w*v.w;
  #pragma unroll
  for (int off=1; off<64; off<<=1){ s += __shfl_xor(s,off); s2 += __shfl_xor(s2,off); }
  __shared__ float ss[4], ss2[4];
  int wave = tid>>6, lane = tid&63;
  if (lane==0){ ss[wave]=s; ss2[wave]=s2; }
  __syncthreads();
  s  = ss[0]+ss[1]+ss[2]+ss[3];
  s2 = ss2[0]+ss2[1]+ss2[2]+ss2[3];
  float mu  = s * (1.0f/D_MODEL);
  float var = s2 * (1.0f/D_MODEL) - mu*mu;
  float rstd = rsqrtf(var + 1e-5f);
  float4 wv = ((const float4*)w)[tid];
  float4 bv = ((const float4*)b)[tid];
  uint2 pk;
  pk.x = pk2bf((v.x-mu)*rstd*wv.x + bv.x, (v.y-mu)*rstd*wv.y + bv.y);
  pk.y = pk2bf((v.z-mu)*rstd*wv.z + bv.z, (v.w-mu)*rstd*wv.w + bv.w);
  *(uint2*)(out + (size_t)row*D_MODEL + tid*4) = pk;
}

// ---------------- GEMM: C[M,N] = A[M,K]bf16 * BT[N,K]bf16^T + epilogue -----
// 128 x BN tile, BK k-tile, 4 waves (2x2). LDS pad-free, 16B chunks
// XOR-swizzled (chunk pos ^ (row&7)). Accumulates C^T (reg r -> col).
// Epilogue stages C via LDS and writes full cache lines.
// MODE 0: bf16 = acc+bias | 1: f32 = acc+bias+res | 2: bf16 = gelu(acc+bias)
template<int MODE, int BN, int BK>
__global__ __launch_bounds__(256, 4) void gemm_bt(const ushort_t* __restrict__ A,
                                                  const ushort_t* __restrict__ BT,
                                                  const float* __restrict__ bias,
                                                  const float* __restrict__ res,
                                                  void* __restrict__ out,
                                                  int M, int N, int K){
  constexpr int NI  = BN/32;          // acc frags per wave in N
  constexpr int CPR = BK/8;           // 16B chunks per row
  constexpr int AG  = 128*CPR/256;    // A staging iterations
  constexpr int BG  = BN*CPR/256;     // B staging iterations
  constexpr int KBYTES = 128*BK*2 + BN*BK*2;
  constexpr int CBYTES = (MODE==1) ? 64*66*4 : 128*132*2;
  constexpr int SBYTES = (KBYTES > CBYTES) ? KBYTES : CBYTES;
  __shared__ __align__(16) char smem[SBYTES];
  ushort_t* As = (ushort_t*)smem;
  ushort_t* Bs = As + 128*BK;
  const int m0 = blockIdx.x*128, n0 = blockIdx.y*BN;
  const int tid = threadIdx.x;
  const int wave = tid >> 6, lane = tid & 63;
  const int wm = (wave >> 1)*64, wn = (wave & 1)*(BN/2);
  const int quad = lane >> 4, l16 = lane & 15;

  f32x4 acc[4][NI] = {};

  for (int k0 = 0; k0 < K; k0 += BK) {
    #pragma unroll
    for (int c = 0; c < AG; ++c) {
      int q   = (c*4 + wave)*64 + lane;
      int row = q / CPR, pos = q % CPR;
      int lc  = pos ^ (row & 7);
      __builtin_amdgcn_global_load_lds(AS1(A + (size_t)(m0+row)*K + k0 + lc*8),
                                       AS3(&As[(c*4+wave)*512]), 16, 0, 0);
    }
    #pragma unroll
    for (int c = 0; c < BG; ++c) {
      int q   = (c*4 + wave)*64 + lane;
      int row = q / CPR, pos = q % CPR;
      int lc  = pos ^ (row & 7);
      __builtin_amdgcn_global_load_lds(AS1(BT + (size_t)(n0+row)*K + k0 + lc*8),
                                       AS3(&Bs[(c*4+wave)*512]), 16, 0, 0);
    }
    __syncthreads();
    #pragma unroll
    for (int kk = 0; kk < BK; kk += 32) {
      bf16x8 af[4], bfr[NI];
      #pragma unroll
      for (int i = 0; i < 4; ++i){
        int row = wm + i*16 + l16;
        int pos = ((kk>>3) + quad) ^ (row & 7);
        af[i] = *(const bf16x8*)(&As[row*BK + pos*8]);
      }
      #pragma unroll
      for (int i = 0; i < NI; ++i){
        int row = wn + i*16 + l16;
        int pos = ((kk>>3) + quad) ^ (row & 7);
        bfr[i] = *(const bf16x8*)(&Bs[row*BK + pos*8]);
      }
      #pragma unroll
      for (int mi = 0; mi < 4; ++mi)
        #pragma unroll
        for (int ni = 0; ni < NI; ++ni)
          acc[mi][ni] = __builtin_amdgcn_mfma_f32_16x16x32_bf16(bfr[ni], af[mi], acc[mi][ni], 0,0,0);
    }
    __syncthreads();
  }

  if constexpr (MODE == 1) {
    // fp32 + residual: two 64-row passes through LDS (64 x 66 f32)
    float* Cf = (float*)smem;
    #pragma unroll
    for (int ph = 0; ph < 2; ++ph){
      if (ph) __syncthreads();
      if (wm == ph*64) {
        #pragma unroll
        for (int ni = 0; ni < NI; ++ni){
          int cb = wn + ni*16 + quad*4;
          float4 b4 = *(const float4*)(bias + n0 + cb);
          #pragma unroll
          for (int mi = 0; mi < 4; ++mi){
            int lm = mi*16 + l16;
            float2 v01 = make_float2(acc[mi][ni][0] + b4.x, acc[mi][ni][1] + b4.y);
            float2 v23 = make_float2(acc[mi][ni][2] + b4.z, acc[mi][ni][3] + b4.w);
            *(float2*)(&Cf[lm*66 + cb])     = v01;
            *(float2*)(&Cf[lm*66 + cb + 2]) = v23;
          }
        }
      }
      __syncthreads();
      int lr = tid >> 2, qq = tid & 3;
      size_t grow = (size_t)(m0 + ph*64 + lr)*N + n0;
      #pragma unroll
      for (int jj = 0; jj < 4; ++jj){
        int cc = (jj*4 + qq)*4;
        float2 a  = *(float2*)(&Cf[lr*66 + cc]);
        float2 c2 = *(float2*)(&Cf[lr*66 + cc + 2]);
        float4 r4 = *(const float4*)(res + grow + cc);
        float4 o4 = make_float4(a.x + r4.x, a.y + r4.y, c2.x + r4.z, c2.y + r4.w);
        *(float4*)((float*)out + grow + cc) = o4;
      }
    }
  } else {
    // bf16: stage full 128 x 128 tile (stride 132), then full-line stores
    ushort_t* Cs = (ushort_t*)smem;
    #pragma unroll
    for (int ni = 0; ni < NI; ++ni){
      int cb = wn + ni*16 + quad*4;
      float4 b4 = *(const float4*)(bias + n0 + cb);
      #pragma unroll
      for (int mi = 0; mi < 4; ++mi){
        int m = wm + mi*16 + l16;
        float v0 = acc[mi][ni][0] + b4.x;
        float v1 = acc[mi][ni][1] + b4.y;
        float v2 = acc[mi][ni][2] + b4.z;
        float v3 = acc[mi][ni][3] + b4.w;
        if constexpr (MODE == 2){
          v0 = 0.5f*v0*(1.0f + erff(v0*0.70710678118654752f));
          v1 = 0.5f*v1*(1.0f + erff(v1*0.70710678118654752f));
          v2 = 0.5f*v2*(1.0f + erff(v2*0.70710678118654752f));
          v3 = 0.5f*v3*(1.0f + erff(v3*0.70710678118654752f));
        }
        uint2 pk; pk.x = pk2bf(v0,v1); pk.y = pk2bf(v2,v3);
        *(uint2*)(&Cs[m*132 + cb]) = pk;
      }
    }
    __syncthreads();
    int r = tid >> 1, hh2 = tid & 1;
    size_t grow = (size_t)(m0 + r)*N + n0 + hh2*64;
    #pragma unroll
    for (int jj = 0; jj < 8; ++jj){
      uint2 a  = *(uint2*)(&Cs[r*132 + hh2*64 + jj*8]);
      uint2 b2 = *(uint2*)(&Cs[r*132 + hh2*64 + jj*8 + 4]);
      uint4 o4 = make_uint4(a.x, a.y, b2.x, b2.y);
      *(uint4*)((ushort_t*)out + grow + jj*8) = o4;
    }
  }
}

// ---------------- V transpose: qkv v-part -> vt [bh][64][T] ----------------
#define LDSS 72
__global__ __launch_bounds__(256) void vtrans(const ushort_t* __restrict__ qkv,
                                              ushort_t* __restrict__ vt){
  __shared__ __align__(16) ushort_t tile[64*LDSS];
  const int bh = blockIdx.x;
  const int b = bh >> 4, h = bh & 15;
  const int t0 = blockIdx.y*64;
  const int tid = threadIdx.x;
  #pragma unroll
  for (int it = 0; it < 2; ++it){
    int idx = it*256 + tid;
    int i = idx >> 3, c = (idx & 7) << 3;
    uint4 vv = *(const uint4*)(qkv + (size_t)(b*TSEQ + t0 + i)*3072 + 2048 + h*64 + c);
    *(uint4*)(&tile[i*LDSS + c]) = vv;
  }
  __syncthreads();
  #pragma unroll
  for (int it = 0; it < 2; ++it){
    int idx = it*256 + tid;
    int j = idx >> 3, ii = (idx & 7) << 3;
    union { unsigned short us[8]; uint4 u4; } pk;
    #pragma unroll
    for (int e = 0; e < 8; ++e) pk.us[e] = tile[(ii+e)*LDSS + j];
    *(uint4*)(vt + (size_t)(bh*64 + j)*TSEQ + t0 + ii) = pk.u4;
  }
}

// ---------------- flash attention (S^T, paired Q-tiles, LDS K/V dbuf) -------
// Block (bh, i): Q-tiles qtA=i and qtB=31-i -> 33 j-tiles/block, constant.
#define PSTR 72
__global__ __launch_bounds__(256) void attn_kernel(const ushort_t* __restrict__ qkv,
                                                   const ushort_t* __restrict__ vt,
                                                   ushort_t* __restrict__ y){
  __shared__ __align__(16) ushort_t Ks[2][64*64];
  __shared__ __align__(16) ushort_t Vs[2][64*64];
  __shared__ __align__(16) ushort_t Plds[4][16*PSTR];
  const int bh = blockIdx.x;
  const int b = bh >> 4, h = bh & 15;
  const int qtA = blockIdx.y;                      // 0..15
  const int qtB = (TSEQ/64 - 1) - qtA;             // 31..16
  const int wave = threadIdx.x >> 6, lane = threadIdx.x & 63;
  const int quad = lane >> 4, l16 = lane & 15;

  const ushort_t* qbase = qkv + (size_t)(b*TSEQ)*3072 + h*64;
  const ushort_t* kbase = qbase + 1024;
  const ushort_t* vbase = vt + (size_t)(bh*64)*TSEQ;
  ushort_t* P = Plds[wave];

  auto stage = [&](int buf, int j0){
    #pragma unroll
    for (int c = 0; c < 2; ++c){
      int q = (wave*2 + c)*64 + lane;
      int row = q >> 3, pos = q & 7;
      int lc = pos ^ (row & 7);
      __builtin_amdgcn_global_load_lds(AS1(kbase + (size_t)(j0+row)*3072 + lc*8),
                                       AS3(&Ks[buf][(wave*2+c)*512]), 16, 0, 0);
      __builtin_amdgcn_global_load_lds(AS1(vbase + (size_t)row*TSEQ + j0 + lc*8),
                                       AS3(&Vs[buf][(wave*2+c)*512]), 16, 0, 0);
    }
  };

  const int qtg[2] = {qtA, qtB};
  int qrow[2];
  bf16x8 qf[2][2];
  #pragma unroll
  for (int g = 0; g < 2; ++g){
    qrow[g] = qtg[g]*64 + wave*16 + l16;
    #pragma unroll
    for (int kk = 0; kk < 2; ++kk)
      qf[g][kk] = *(const bf16x8*)(qbase + (size_t)qrow[g]*3072 + kk*32 + quad*8);
  }

  float m_i[2] = {-3e38f, -3e38f}, l_i[2] = {0.f, 0.f};
  f32x4 o[2][4] = {};
  const float cs = 0.18033688011112042f;           // (1/8) * log2(e)

  const int ntiles = qtB + 1;                      // B's j-range (superset)
  stage(0, 0);
  for (int it = 0; it < ntiles; ++it) {
    const int cur = it & 1;
    const int j0 = it * 64;
    __syncthreads();                               // staged buf `cur` ready
    if (it + 1 < ntiles) stage(cur ^ 1, j0 + 64);
    #pragma unroll
    for (int g = 0; g < 2; ++g){
      if (g == 0 && it > qtA) continue;            // A done past its diagonal
      f32x4 s[4] = {};
      #pragma unroll
      for (int kk = 0; kk < 2; ++kk){
        #pragma unroll
        for (int nj = 0; nj < 4; ++nj){
          int row = nj*16 + l16;
          int pos = (kk*4 + quad) ^ (row & 7);
          bf16x8 kf = *(const bf16x8*)(&Ks[cur][row*64 + pos*8]);
          s[nj] = __builtin_amdgcn_mfma_f32_16x16x32_bf16(kf, qf[g][kk], s[nj], 0,0,0);
        }
      }
      if (it == qtg[g]) {                          // this group's diagonal tile
        #pragma unroll
        for (int nj = 0; nj < 4; ++nj)
          #pragma unroll
          for (int r = 0; r < 4; ++r){
            int jc = j0 + nj*16 + quad*4 + r;
            if (jc > qrow[g]) s[nj][r] = -3e38f;
          }
      }
      float mloc = s[0][0];
      #pragma unroll
      for (int nj = 0; nj < 4; ++nj)
        #pragma unroll
        for (int r = 0; r < 4; ++r) mloc = fmaxf(mloc, s[nj][r]);
      mloc = fmaxf(mloc, __shfl_xor(mloc, 16));
      mloc = fmaxf(mloc, __shfl_xor(mloc, 32));
      float mn = fmaxf(m_i[g], mloc);
      float alpha = __builtin_amdgcn_exp2f((m_i[g] - mn)*cs);
      m_i[g] = mn;
      float rs = 0.f;
      #pragma unroll
      for (int nj = 0; nj < 4; ++nj){
        float p0 = __builtin_amdgcn_exp2f((s[nj][0]-mn)*cs);
        float p1 = __builtin_amdgcn_exp2f((s[nj][1]-mn)*cs);
        float p2 = __builtin_amdgcn_exp2f((s[nj][2]-mn)*cs);
        float p3 = __builtin_amdgcn_exp2f((s[nj][3]-mn)*cs);
        rs += (p0+p1)+(p2+p3);
        uint2 pk; pk.x = pk2bf(p0,p1); pk.y = pk2bf(p2,p3);
        *(uint2*)(&P[l16*PSTR + nj*16 + quad*4]) = pk;   // P^T[m][j]
      }
      rs += __shfl_xor(rs, 16);
      rs += __shfl_xor(rs, 32);
      l_i[g] = l_i[g]*alpha + rs;
      #pragma unroll
      for (int dj = 0; dj < 4; ++dj)
        #pragma unroll
        for (int r = 0; r < 4; ++r) o[g][dj][r] *= alpha;
      bf16x8 pf[2];
      #pragma unroll
      for (int kk = 0; kk < 2; ++kk)
        pf[kk] = *(const bf16x8*)(&P[l16*PSTR + kk*32 + quad*8]);
      #pragma unroll
      for (int kk = 0; kk < 2; ++kk){
        #pragma unroll
        for (int dj = 0; dj < 4; ++dj){
          int row = dj*16 + l16;
          int pos = (kk*4 + quad) ^ (row & 7);
          bf16x8 vf = *(const bf16x8*)(&Vs[cur][row*64 + pos*8]);
          o[g][dj] = __builtin_amdgcn_mfma_f32_16x16x32_bf16(vf, pf[kk], o[g][dj], 0,0,0);
        }
      }
    }
  }
  #pragma unroll
  for (int g = 0; g < 2; ++g){
    float inv = 1.0f / l_i[g];
    ushort_t* yr = y + (size_t)(b*TSEQ + qrow[g])*D_MODEL + h*64;
    #pragma unroll
    for (int dj = 0; dj < 4; ++dj){
      uint2 pk;
      pk.x = pk2bf(o[g][dj][0]*inv, o[g][dj][1]*inv);
      pk.y = pk2bf(o[g][dj][2]*inv, o[g][dj][3]*inv);
      *(uint2*)(yr + dj*16 + quad*4) = pk;
    }
  }
}

// ---------------- launcher --------------------------------------------------
extern "C" void kernel_launch(void* const* d_in, const int* in_sizes, int n_in,
                              void* d_out, int out_size, void* d_ws, size_t ws_size,
                              hipStream_t stream)
{
  (void)in_sizes; (void)n_in; (void)out_size; (void)ws_size;
  const float* x      = (const float*)d_in[0];
  const float* ln1_w  = (const float*)d_in[1];
  const float* ln1_b  = (const float*)d_in[2];
  const float* ln2_w  = (const float*)d_in[3];
  const float* ln2_b  = (const float*)d_in[4];
  const float* w_attn = (const float*)d_in[5];
  const float* b_attn = (const float*)d_in[6];
  const float* w_proj = (const float*)d_in[7];
  const float* b_proj = (const float*)d_in[8];
  const float* w_fc   = (const float*)d_in[9];
  const float* b_fc   = (const float*)d_in[10];
  const float* w_fc2  = (const float*)d_in[11];
  const float* b_fc2  = (const float*)d_in[12];
  float* out = (float*)d_out;

  char* p = (char*)d_ws;
  auto alloc = [&](size_t n){ char* r = p; p += (n + 255) & ~(size_t)255; return (void*)r; };
  ushort_t* wAT  = (ushort_t*)alloc((size_t)3072*1024*2);
  ushort_t* wPT  = (ushort_t*)alloc((size_t)1024*1024*2);
  ushort_t* wFT  = (ushort_t*)alloc((size_t)4096*1024*2);
  ushort_t* wF2T = (ushort_t*)alloc((size_t)1024*4096*2);
  ushort_t* hbuf = (ushort_t*)alloc((size_t)NTOK*D_MODEL*2);
  ushort_t* qkv  = (ushort_t*)alloc((size_t)NTOK*4096*2);   // qkv, later fc1 out
  ushort_t* vt   = (ushort_t*)alloc((size_t)32*64*TSEQ*2);
  ushort_t* ybuf = (ushort_t*)alloc((size_t)NTOK*D_MODEL*2);
  float*    x1   = (float*)   alloc((size_t)NTOK*D_MODEL*4);
  ushort_t* hh   = qkv;

  wtrans_all<<<12288, 256, 0, stream>>>(w_attn, wAT, w_proj, wPT, w_fc, wFT, w_fc2, wF2T);

  ln_kernel<<<NTOK, 256, 0, stream>>>(x, ln1_w, ln1_b, hbuf);
  gemm_bt<0,128,64><<<dim3(NTOK/128, 3072/128), 256, 0, stream>>>(hbuf, wAT, b_attn, nullptr, qkv, NTOK, 3072, 1024);
  vtrans<<<dim3(32, TSEQ/64), 256, 0, stream>>>(qkv, vt);
  attn_kernel<<<dim3(32, TSEQ/128), 256, 0, stream>>>(qkv, vt, ybuf);
  gemm_bt<1,64,128><<<dim3(NTOK/128, 1024/64), 256, 0, stream>>>(ybuf, wPT, b_proj, x, x1, NTOK, 1024, 1024);
  ln_kernel<<<NTOK, 256, 0, stream>>>(x1, ln2_w, ln2_b, hbuf);
  gemm_bt<2,128,64><<<dim3(NTOK/128, 4096/128), 256, 0, stream>>>(hbuf, wFT, b_fc, nullptr, hh, NTOK, 4096, 1024);
  gemm_bt<1,64,128><<<dim3(NTOK/128, 1024/64), 256, 0, stream>>>(hh, wF2T, b_fc2, x1, out, NTOK, 1024, 4096);
}

// Round 9
// 319.290 us; speedup vs baseline: 1.1636x; 1.0352x over previous
//
#include <hip/hip_runtime.h>
#include <cstdint>
#include <cstddef>

// TransformerBlock on MI355X (gfx950). bf16 MFMA everywhere, fp32 spine.
// R9: MODE=1 GEMMs (proj, FC2) get the attention kernel's single-barrier
//     double-buffered pipeline (stage k+1 right after the barrier, compute k,
//     next barrier's vmcnt drain has a full compute-phase to hide the load).
//     BK back to 64 (R8's BK=128 read pattern cost 6.4M LDS bank conflicts).
//     2x24.5KB LDS = 49KB -> still 2 blocks/CU (grid-capped anyway).
//     QKV/FC1 keep the 4-blocks/CU 2-barrier form (m132 lesson).

#define D_MODEL 1024
#define TSEQ    2048
#define BATCH   2
#define NHEADS  16
#define NTOK    (BATCH*TSEQ)   // 4096

typedef __attribute__((ext_vector_type(8))) short bf16x8;
typedef __attribute__((ext_vector_type(4))) float f32x4;
typedef unsigned short ushort_t;

#define AS3(p) ((__attribute__((address_space(3))) unsigned int*)(p))
#define AS1(p) ((const __attribute__((address_space(1))) unsigned int*)(p))

__device__ __forceinline__ unsigned short f2bf(float f){
  union { float f; unsigned u; } v; v.f = f;
  unsigned r = v.u + 0x7fffu + ((v.u >> 16) & 1u);
  return (unsigned short)(r >> 16);
}
__device__ __forceinline__ unsigned pk2bf(float a, float b){
  union { float f; unsigned u; } x, y; x.f = a; y.f = b;
  return __builtin_amdgcn_perm(y.u + 0x8000u, x.u + 0x8000u, 0x07060302u);
}

// ------------- fused weight convert+transpose: fp32 [K][N] -> bf16 [N][K] ---
__global__ __launch_bounds__(256) void wtrans_all(
    const float* __restrict__ w0, ushort_t* __restrict__ o0,
    const float* __restrict__ w1, ushort_t* __restrict__ o1,
    const float* __restrict__ w2, ushort_t* __restrict__ o2,
    const float* __restrict__ w3, ushort_t* __restrict__ o3){
  __shared__ float tile[32][33];
  int bid = blockIdx.x;
  const float* in; ushort_t* out; int K, N, t;
  if (bid < 3072)      { in=w0; out=o0; K=1024; N=3072; t=bid; }
  else if (bid < 4096) { in=w1; out=o1; K=1024; N=1024; t=bid-3072; }
  else if (bid < 8192) { in=w2; out=o2; K=1024; N=4096; t=bid-4096; }
  else                 { in=w3; out=o3; K=4096; N=1024; t=bid-8192; }
  int tx_n = N >> 5;
  int n0 = (t % tx_n)*32, k0 = (t / tx_n)*32;
  int tx = threadIdx.x & 31, ty = threadIdx.x >> 5;   // 32 x 8
  #pragma unroll
  for (int i=0;i<32;i+=8)
    tile[ty+i][tx] = in[(size_t)(k0+ty+i)*N + n0+tx];
  __syncthreads();
  #pragma unroll
  for (int i=0;i<32;i+=8)
    out[(size_t)(n0+ty+i)*K + k0+tx] = f2bf(tile[tx][ty+i]);
}

// ---------------- layernorm: fp32 row[1024] -> bf16 ------------------------
__global__ __launch_bounds__(256) void ln_kernel(const float* __restrict__ x,
                                                 const float* __restrict__ w,
                                                 const float* __restrict__ b,
                                                 ushort_t* __restrict__ out){
  int row = blockIdx.x;
  int tid = threadIdx.x;
  const float* xr = x + (size_t)row*D_MODEL;
  float4 v = ((const float4*)xr)[tid];
  float s  = v.x+v.y+v.z+v.w;
  float s2 = v.x*v.x+v.y*v.y+v.z*v.z+v.w*v.w;
  #pragma unroll
  for (int off=1; off<64; off<<=1){ s += __shfl_xor(s,off); s2 += __shfl_xor(s2,off); }
  __shared__ float ss[4], ss2[4];
  int wave = tid>>6, lane = tid&63;
  if (lane==0){ ss[wave]=s; ss2[wave]=s2; }
  __syncthreads();
  s  = ss[0]+ss[1]+ss[2]+ss[3];
  s2 = ss2[0]+ss2[1]+ss2[2]+ss2[3];
  float mu  = s * (1.0f/D_MODEL);
  float var = s2 * (1.0f/D_MODEL) - mu*mu;
  float rstd = rsqrtf(var + 1e-5f);
  float4 wv = ((const float4*)w)[tid];
  float4 bv = ((const float4*)b)[tid];
  uint2 pk;
  pk.x = pk2bf((v.x-mu)*rstd*wv.x + bv.x, (v.y-mu)*rstd*wv.y + bv.y);
  pk.y = pk2bf((v.z-mu)*rstd*wv.z + bv.z, (v.w-mu)*rstd*wv.w + bv.w);
  *(uint2*)(out + (size_t)row*D_MODEL + tid*4) = pk;
}

// ---------------- GEMM: C[M,N] = A[M,K]bf16 * BT[N,K]bf16^T + epilogue -----
// 128 x BN tile, BK=64 k-tile, 4 waves (2x2). LDS pad-free, 16B chunks
// XOR-swizzled. Accumulates C^T (reg r -> col). Epilogue via LDS, full-line
// stores. DB=1: double-buffered single-barrier pipelined K-loop.
// MODE 0: bf16 = acc+bias | 1: f32 = acc+bias+res | 2: bf16 = gelu(acc+bias)
template<int MODE, int BN, int DB>
__global__ __launch_bounds__(256, 4) void gemm_bt(const ushort_t* __restrict__ A,
                                                  const ushort_t* __restrict__ BT,
                                                  const float* __restrict__ bias,
                                                  const float* __restrict__ res,
                                                  void* __restrict__ out,
                                                  int M, int N, int K){
  constexpr int BK  = 64;
  constexpr int NI  = BN/32;          // acc frags per wave in N
  constexpr int AG  = 4;              // A staging iterations (128*8/256)
  constexpr int BG  = BN/32;          // B staging iterations
  constexpr int NBUF = DB ? 2 : 1;
  constexpr int ASZ = 128*BK, BSZ = BN*BK;
  constexpr int KBYTES = NBUF*(ASZ+BSZ)*2;
  constexpr int CBYTES = (MODE==1) ? 64*66*4 : 128*132*2;
  constexpr int SBYTES = (KBYTES > CBYTES) ? KBYTES : CBYTES;
  __shared__ __align__(16) char smem[SBYTES];
  ushort_t* As = (ushort_t*)smem;          // [NBUF][ASZ]
  ushort_t* Bs = As + NBUF*ASZ;            // [NBUF][BSZ]
  const int m0 = blockIdx.x*128, n0 = blockIdx.y*BN;
  const int tid = threadIdx.x;
  const int wave = tid >> 6, lane = tid & 63;
  const int wm = (wave >> 1)*64, wn = (wave & 1)*(BN/2);
  const int quad = lane >> 4, l16 = lane & 15;

  f32x4 acc[4][NI] = {};

  auto stage = [&](int buf, int k0){
    #pragma unroll
    for (int c = 0; c < AG; ++c) {
      int q   = (c*4 + wave)*64 + lane;
      int row = q >> 3, pos = q & 7;
      int lc  = pos ^ (row & 7);
      __builtin_amdgcn_global_load_lds(AS1(A + (size_t)(m0+row)*K + k0 + lc*8),
                                       AS3(&As[buf*ASZ + (c*4+wave)*512]), 16, 0, 0);
    }
    #pragma unroll
    for (int c = 0; c < BG; ++c) {
      int q   = (c*4 + wave)*64 + lane;
      int row = q >> 3, pos = q & 7;
      int lc  = pos ^ (row & 7);
      __builtin_amdgcn_global_load_lds(AS1(BT + (size_t)(n0+row)*K + k0 + lc*8),
                                       AS3(&Bs[buf*BSZ + (c*4+wave)*512]), 16, 0, 0);
    }
  };

  auto compute = [&](int buf){
    #pragma unroll
    for (int kk = 0; kk < BK; kk += 32) {
      bf16x8 af[4], bfr[NI];
      #pragma unroll
      for (int i = 0; i < 4; ++i){
        int row = wm + i*16 + l16;
        int pos = ((kk>>3) + quad) ^ (row & 7);
        af[i] = *(const bf16x8*)(&As[buf*ASZ + row*BK + pos*8]);
      }
      #pragma unroll
      for (int i = 0; i < NI; ++i){
        int row = wn + i*16 + l16;
        int pos = ((kk>>3) + quad) ^ (row & 7);
        bfr[i] = *(const bf16x8*)(&Bs[buf*BSZ + row*BK + pos*8]);
      }
      #pragma unroll
      for (int mi = 0; mi < 4; ++mi)
        #pragma unroll
        for (int ni = 0; ni < NI; ++ni)
          acc[mi][ni] = __builtin_amdgcn_mfma_f32_16x16x32_bf16(bfr[ni], af[mi], acc[mi][ni], 0,0,0);
    }
  };

  if constexpr (DB) {
    const int nk = K / BK;
    stage(0, 0);
    for (int ki = 0; ki < nk; ++ki) {
      const int cur = ki & 1;
      __syncthreads();                       // buf `cur` landed (prev iter's stage)
      if (ki + 1 < nk) stage(cur ^ 1, (ki+1)*BK);
      compute(cur);
    }
    __syncthreads();                         // guard smem reuse by epilogue
  } else {
    for (int k0 = 0; k0 < K; k0 += BK) {
      stage(0, k0);
      __syncthreads();
      compute(0);
      __syncthreads();
    }
  }

  if constexpr (MODE == 1) {
    // fp32 + residual: two 64-row passes through LDS (64 x 66 f32)
    float* Cf = (float*)smem;
    #pragma unroll
    for (int ph = 0; ph < 2; ++ph){
      if (ph) __syncthreads();
      if (wm == ph*64) {
        #pragma unroll
        for (int ni = 0; ni < NI; ++ni){
          int cb = wn + ni*16 + quad*4;
          float4 b4 = *(const float4*)(bias + n0 + cb);
          #pragma unroll
          for (int mi = 0; mi < 4; ++mi){
            int lm = mi*16 + l16;
            float2 v01 = make_float2(acc[mi][ni][0] + b4.x, acc[mi][ni][1] + b4.y);
            float2 v23 = make_float2(acc[mi][ni][2] + b4.z, acc[mi][ni][3] + b4.w);
            *(float2*)(&Cf[lm*66 + cb])     = v01;
            *(float2*)(&Cf[lm*66 + cb + 2]) = v23;
          }
        }
      }
      __syncthreads();
      int lr = tid >> 2, qq = tid & 3;
      size_t grow = (size_t)(m0 + ph*64 + lr)*N + n0;
      #pragma unroll
      for (int jj = 0; jj < 4; ++jj){
        int cc = (jj*4 + qq)*4;
        float2 a  = *(float2*)(&Cf[lr*66 + cc]);
        float2 c2 = *(float2*)(&Cf[lr*66 + cc + 2]);
        float4 r4 = *(const float4*)(res + grow + cc);
        float4 o4 = make_float4(a.x + r4.x, a.y + r4.y, c2.x + r4.z, c2.y + r4.w);
        *(float4*)((float*)out + grow + cc) = o4;
      }
    }
  } else {
    // bf16: stage full 128 x 128 tile (stride 132), then full-line stores
    ushort_t* Cs = (ushort_t*)smem;
    #pragma unroll
    for (int ni = 0; ni < NI; ++ni){
      int cb = wn + ni*16 + quad*4;
      float4 b4 = *(const float4*)(bias + n0 + cb);
      #pragma unroll
      for (int mi = 0; mi < 4; ++mi){
        int m = wm + mi*16 + l16;
        float v0 = acc[mi][ni][0] + b4.x;
        float v1 = acc[mi][ni][1] + b4.y;
        float v2 = acc[mi][ni][2] + b4.z;
        float v3 = acc[mi][ni][3] + b4.w;
        if constexpr (MODE == 2){
          v0 = 0.5f*v0*(1.0f + erff(v0*0.70710678118654752f));
          v1 = 0.5f*v1*(1.0f + erff(v1*0.70710678118654752f));
          v2 = 0.5f*v2*(1.0f + erff(v2*0.70710678118654752f));
          v3 = 0.5f*v3*(1.0f + erff(v3*0.70710678118654752f));
        }
        uint2 pk; pk.x = pk2bf(v0,v1); pk.y = pk2bf(v2,v3);
        *(uint2*)(&Cs[m*132 + cb]) = pk;
      }
    }
    __syncthreads();
    int r = tid >> 1, hh2 = tid & 1;
    size_t grow = (size_t)(m0 + r)*N + n0 + hh2*64;
    #pragma unroll
    for (int jj = 0; jj < 8; ++jj){
      uint2 a  = *(uint2*)(&Cs[r*132 + hh2*64 + jj*8]);
      uint2 b2 = *(uint2*)(&Cs[r*132 + hh2*64 + jj*8 + 4]);
      uint4 o4 = make_uint4(a.x, a.y, b2.x, b2.y);
      *(uint4*)((ushort_t*)out + grow + jj*8) = o4;
    }
  }
}

// ---------------- V transpose: qkv v-part -> vt [bh][64][T] ----------------
#define LDSS 72
__global__ __launch_bounds__(256) void vtrans(const ushort_t* __restrict__ qkv,
                                              ushort_t* __restrict__ vt){
  __shared__ __align__(16) ushort_t tile[64*LDSS];
  const int bh = blockIdx.x;
  const int b = bh >> 4, h = bh & 15;
  const int t0 = blockIdx.y*64;
  const int tid = threadIdx.x;
  #pragma unroll
  for (int it = 0; it < 2; ++it){
    int idx = it*256 + tid;
    int i = idx >> 3, c = (idx & 7) << 3;
    uint4 vv = *(const uint4*)(qkv + (size_t)(b*TSEQ + t0 + i)*3072 + 2048 + h*64 + c);
    *(uint4*)(&tile[i*LDSS + c]) = vv;
  }
  __syncthreads();
  #pragma unroll
  for (int it = 0; it < 2; ++it){
    int idx = it*256 + tid;
    int j = idx >> 3, ii = (idx & 7) << 3;
    union { unsigned short us[8]; uint4 u4; } pk;
    #pragma unroll
    for (int e = 0; e < 8; ++e) pk.us[e] = tile[(ii+e)*LDSS + j];
    *(uint4*)(vt + (size_t)(bh*64 + j)*TSEQ + t0 + ii) = pk.u4;
  }
}

// ---------------- flash attention (S^T, paired Q-tiles, LDS K/V dbuf) -------
// Block (bh, i): Q-tiles qtA=i and qtB=31-i -> 33 j-tiles/block, constant.
#define PSTR 72
__global__ __launch_bounds__(256) void attn_kernel(const ushort_t* __restrict__ qkv,
                                                   const ushort_t* __restrict__ vt,
                                                   ushort_t* __restrict__ y){
  __shared__ __align__(16) ushort_t Ks[2][64*64];
  __shared__ __align__(16) ushort_t Vs[2][64*64];
  __shared__ __align__(16) ushort_t Plds[4][16*PSTR];
  const int bh = blockIdx.x;
  const int b = bh >> 4, h = bh & 15;
  const int qtA = blockIdx.y;                      // 0..15
  const int qtB = (TSEQ/64 - 1) - qtA;             // 31..16
  const int wave = threadIdx.x >> 6, lane = threadIdx.x & 63;
  const int quad = lane >> 4, l16 = lane & 15;

  const ushort_t* qbase = qkv + (size_t)(b*TSEQ)*3072 + h*64;
  const ushort_t* kbase = qbase + 1024;
  const ushort_t* vbase = vt + (size_t)(bh*64)*TSEQ;
  ushort_t* P = Plds[wave];

  auto stage = [&](int buf, int j0){
    #pragma unroll
    for (int c = 0; c < 2; ++c){
      int q = (wave*2 + c)*64 + lane;
      int row = q >> 3, pos = q & 7;
      int lc = pos ^ (row & 7);
      __builtin_amdgcn_global_load_lds(AS1(kbase + (size_t)(j0+row)*3072 + lc*8),
                                       AS3(&Ks[buf][(wave*2+c)*512]), 16, 0, 0);
      __builtin_amdgcn_global_load_lds(AS1(vbase + (size_t)row*TSEQ + j0 + lc*8),
                                       AS3(&Vs[buf][(wave*2+c)*512]), 16, 0, 0);
    }
  };

  const int qtg[2] = {qtA, qtB};
  int qrow[2];
  bf16x8 qf[2][2];
  #pragma unroll
  for (int g = 0; g < 2; ++g){
    qrow[g] = qtg[g]*64 + wave*16 + l16;
    #pragma unroll
    for (int kk = 0; kk < 2; ++kk)
      qf[g][kk] = *(const bf16x8*)(qbase + (size_t)qrow[g]*3072 + kk*32 + quad*8);
  }

  float m_i[2] = {-3e38f, -3e38f}, l_i[2] = {0.f, 0.f};
  f32x4 o[2][4] = {};
  const float cs = 0.18033688011112042f;           // (1/8) * log2(e)

  const int ntiles = qtB + 1;                      // B's j-range (superset)
  stage(0, 0);
  for (int it = 0; it < ntiles; ++it) {
    const int cur = it & 1;
    const int j0 = it * 64;
    __syncthreads();                               // staged buf `cur` ready
    if (it + 1 < ntiles) stage(cur ^ 1, j0 + 64);
    #pragma unroll
    for (int g = 0; g < 2; ++g){
      if (g == 0 && it > qtA) continue;            // A done past its diagonal
      f32x4 s[4] = {};
      #pragma unroll
      for (int kk = 0; kk < 2; ++kk){
        #pragma unroll
        for (int nj = 0; nj < 4; ++nj){
          int row = nj*16 + l16;
          int pos = (kk*4 + quad) ^ (row & 7);
          bf16x8 kf = *(const bf16x8*)(&Ks[cur][row*64 + pos*8]);
          s[nj] = __builtin_amdgcn_mfma_f32_16x16x32_bf16(kf, qf[g][kk], s[nj], 0,0,0);
        }
      }
      if (it == qtg[g]) {                          // this group's diagonal tile
        #pragma unroll
        for (int nj = 0; nj < 4; ++nj)
          #pragma unroll
          for (int r = 0; r < 4; ++r){
            int jc = j0 + nj*16 + quad*4 + r;
            if (jc > qrow[g]) s[nj][r] = -3e38f;
          }
      }
      float mloc = s[0][0];
      #pragma unroll
      for (int nj = 0; nj < 4; ++nj)
        #pragma unroll
        for (int r = 0; r < 4; ++r) mloc = fmaxf(mloc, s[nj][r]);
      mloc = fmaxf(mloc, __shfl_xor(mloc, 16));
      mloc = fmaxf(mloc, __shfl_xor(mloc, 32));
      float mn = fmaxf(m_i[g], mloc);
      float alpha = __builtin_amdgcn_exp2f((m_i[g] - mn)*cs);
      m_i[g] = mn;
      float rs = 0.f;
      #pragma unroll
      for (int nj = 0; nj < 4; ++nj){
        float p0 = __builtin_amdgcn_exp2f((s[nj][0]-mn)*cs);
        float p1 = __builtin_amdgcn_exp2f((s[nj][1]-mn)*cs);
        float p2 = __builtin_amdgcn_exp2f((s[nj][2]-mn)*cs);
        float p3 = __builtin_amdgcn_exp2f((s[nj][3]-mn)*cs);
        rs += (p0+p1)+(p2+p3);
        uint2 pk; pk.x = pk2bf(p0,p1); pk.y = pk2bf(p2,p3);
        *(uint2*)(&P[l16*PSTR + nj*16 + quad*4]) = pk;   // P^T[m][j]
      }
      rs += __shfl_xor(rs, 16);
      rs += __shfl_xor(rs, 32);
      l_i[g] = l_i[g]*alpha + rs;
      #pragma unroll
      for (int dj = 0; dj < 4; ++dj)
        #pragma unroll
        for (int r = 0; r < 4; ++r) o[g][dj][r] *= alpha;
      bf16x8 pf[2];
      #pragma unroll
      for (int kk = 0; kk < 2; ++kk)
        pf[kk] = *(const bf16x8*)(&P[l16*PSTR + kk*32 + quad*8]);
      #pragma unroll
      for (int kk = 0; kk < 2; ++kk){
        #pragma unroll
        for (int dj = 0; dj < 4; ++dj){
          int row = dj*16 + l16;
          int pos = (kk*4 + quad) ^ (row & 7);
          bf16x8 vf = *(const bf16x8*)(&Vs[cur][row*64 + pos*8]);
          o[g][dj] = __builtin_amdgcn_mfma_f32_16x16x32_bf16(vf, pf[kk], o[g][dj], 0,0,0);
        }
      }
    }
  }
  #pragma unroll
  for (int g = 0; g < 2; ++g){
    float inv = 1.0f / l_i[g];
    ushort_t* yr = y + (size_t)(b*TSEQ + qrow[g])*D_MODEL + h*64;
    #pragma unroll
    for (int dj = 0; dj < 4; ++dj){
      uint2 pk;
      pk.x = pk2bf(o[g][dj][0]*inv, o[g][dj][1]*inv);
      pk.y = pk2bf(o[g][dj][2]*inv, o[g][dj][3]*inv);
      *(uint2*)(yr + dj*16 + quad*4) = pk;
    }
  }
}

// ---------------- launcher --------------------------------------------------
extern "C" void kernel_launch(void* const* d_in, const int* in_sizes, int n_in,
                              void* d_out, int out_size, void* d_ws, size_t ws_size,
                              hipStream_t stream)
{
  (void)in_sizes; (void)n_in; (void)out_size; (void)ws_size;
  const float* x      = (const float*)d_in[0];
  const float* ln1_w  = (const float*)d_in[1];
  const float* ln1_b  = (const float*)d_in[2];
  const float* ln2_w  = (const float*)d_in[3];
  const float* ln2_b  = (const float*)d_in[4];
  const float* w_attn = (const float*)d_in[5];
  const float* b_attn = (const float*)d_in[6];
  const float* w_proj = (const float*)d_in[7];
  const float* b_proj = (const float*)d_in[8];
  const float* w_fc   = (const float*)d_in[9];
  const float* b_fc   = (const float*)d_in[10];
  const float* w_fc2  = (const float*)d_in[11];
  const float* b_fc2  = (const float*)d_in[12];
  float* out = (float*)d_out;

  char* p = (char*)d_ws;
  auto alloc = [&](size_t n){ char* r = p; p += (n + 255) & ~(size_t)255; return (void*)r; };
  ushort_t* wAT  = (ushort_t*)alloc((size_t)3072*1024*2);
  ushort_t* wPT  = (ushort_t*)alloc((size_t)1024*1024*2);
  ushort_t* wFT  = (ushort_t*)alloc((size_t)4096*1024*2);
  ushort_t* wF2T = (ushort_t*)alloc((size_t)1024*4096*2);
  ushort_t* hbuf = (ushort_t*)alloc((size_t)NTOK*D_MODEL*2);
  ushort_t* qkv  = (ushort_t*)alloc((size_t)NTOK*4096*2);   // qkv, later fc1 out
  ushort_t* vt   = (ushort_t*)alloc((size_t)32*64*TSEQ*2);
  ushort_t* ybuf = (ushort_t*)alloc((size_t)NTOK*D_MODEL*2);
  float*    x1   = (float*)   alloc((size_t)NTOK*D_MODEL*4);
  ushort_t* hh   = qkv;

  wtrans_all<<<12288, 256, 0, stream>>>(w_attn, wAT, w_proj, wPT, w_fc, wFT, w_fc2, wF2T);

  ln_kernel<<<NTOK, 256, 0, stream>>>(x, ln1_w, ln1_b, hbuf);
  gemm_bt<0,128,0><<<dim3(NTOK/128, 3072/128), 256, 0, stream>>>(hbuf, wAT, b_attn, nullptr, qkv, NTOK, 3072, 1024);
  vtrans<<<dim3(32, TSEQ/64), 256, 0, stream>>>(qkv, vt);
  attn_kernel<<<dim3(32, TSEQ/128), 256, 0, stream>>>(qkv, vt, ybuf);
  gemm_bt<1,64,1><<<dim3(NTOK/128, 1024/64), 256, 0, stream>>>(ybuf, wPT, b_proj, x, x1, NTOK, 1024, 1024);
  ln_kernel<<<NTOK, 256, 0, stream>>>(x1, ln2_w, ln2_b, hbuf);
  gemm_bt<2,128,0><<<dim3(NTOK/128, 4096/128), 256, 0, stream>>>(hbuf, wFT, b_fc, nullptr, hh, NTOK, 4096, 1024);
  gemm_bt<1,64,1><<<dim3(NTOK/128, 1024/64), 256, 0, stream>>>(hh, wF2T, b_fc2, x1, out, NTOK, 1024, 4096);
}